// Round 2
// baseline (3145.948 us; speedup 1.0000x reference)
//
#include <hip/hip_runtime.h>
#include <cstdint>
#include <cstddef>

#define B_ 16
#define D_ 128
#define T_ 4500
#define N_ (B_*T_)      // 72000
#define K_ 1024
#define L_ 8

#define BM 128
#define BN 128
#define BK 16

// ---------------- helpers ----------------
__device__ __forceinline__ bool better(float va, int ja, float vb, int jb) {
  return (va < vb) || (va == vb && ja < jb);
}

// numpy pairwise_sum (n=128 <= PW_BLOCKSIZE path) of fl(x[d]*x[d]):
// r[c] = a[c] + a[c+8] + ... + a[c+120] sequentially, then
// ((r0+r1)+(r2+r3)) + ((r4+r5)+(r6+r7)).  __f*_rn blocks FMA contraction.
__device__ __forceinline__ float pairwise_sq_sum128(const float* __restrict__ x) {
  float r[8];
#pragma unroll
  for (int c = 0; c < 8; ++c) r[c] = __fmul_rn(x[c], x[c]);
#pragma unroll
  for (int i = 1; i < 16; ++i) {
#pragma unroll
    for (int c = 0; c < 8; ++c)
      r[c] = __fadd_rn(r[c], __fmul_rn(x[8*i + c], x[8*i + c]));
  }
  return __fadd_rn(__fadd_rn(__fadd_rn(r[0], r[1]), __fadd_rn(r[2], r[3])),
                   __fadd_rn(__fadd_rn(r[4], r[5]), __fadd_rn(r[6], r[7])));
}

// ---------------- transpose z [B][D][T] -> R [N][D] ----------------
__global__ __launch_bounds__(256)
void k_transpose_z(const float* __restrict__ z, float* __restrict__ R) {
  __shared__ float tile[32][33];
  const int t0 = blockIdx.x * 32;
  const int d0 = blockIdx.y * 32;
  const int b  = blockIdx.z;
  const int tid = threadIdx.x;
  {
    const int jj = tid & 31; const int ii0 = (tid >> 5) * 4;
#pragma unroll
    for (int r = 0; r < 4; ++r) {
      const int ii = ii0 + r;
      float v = 0.f;
      if (t0 + jj < T_) v = z[((size_t)(b*D_ + d0 + ii))*T_ + t0 + jj];
      tile[ii][jj] = v;
    }
  }
  __syncthreads();
  {
    const int ii = tid & 31; const int jj0 = (tid >> 5) * 4;
#pragma unroll
    for (int r = 0; r < 4; ++r) {
      const int jj = jj0 + r;
      if (t0 + jj < T_)
        R[((size_t)(b*T_ + t0 + jj))*D_ + d0 + ii] = tile[ii][jj];
    }
  }
}

// ---------------- transpose cb [L][K][D] -> cbT [L][D][K] ----------------
__global__ __launch_bounds__(256)
void k_transpose_cb(const float* __restrict__ cb, float* __restrict__ cbT) {
  __shared__ float tile[32][33];
  const int j0 = blockIdx.x * 32;
  const int d0 = blockIdx.y * 32;
  const int l  = blockIdx.z;
  const int tid = threadIdx.x;
  {
    const int dd = tid & 31; const int jj0 = (tid >> 5) * 4;
#pragma unroll
    for (int r = 0; r < 4; ++r)
      tile[jj0 + r][dd] = cb[((size_t)(l*K_ + j0 + jj0 + r))*D_ + d0 + dd];
  }
  __syncthreads();
  {
    const int jj = tid & 31; const int dd0 = (tid >> 5) * 4;
#pragma unroll
    for (int r = 0; r < 4; ++r)
      cbT[((size_t)(l*D_ + d0 + dd0 + r))*K_ + j0 + jj] = tile[jj][dd0 + r];
  }
}

// ---------------- per-code squared norms, numpy-pairwise f32 ----------------
__global__ __launch_bounds__(256)
void k_y2(const float* __restrict__ cb, float* __restrict__ y2f) {
  const int row = blockIdx.x * 256 + threadIdx.x;   // 0 .. L_*K_-1
  if (row >= L_ * K_) return;
  y2f[row] = pairwise_sq_sum128(&cb[(size_t)row * D_]);
}

// ---------------- the fused layer kernel ----------------
// dist_j for row n:  fl32( fl32(x2_n + y2_j) - fl32(2 * dot_nj) ), with
// dot accumulated as a strict sequential f32 FMA chain over k=0..127
// (matching BLAS sgemm microkernel semantics). argmin with lowest-index
// tie-break (np.argmin). Then residual -= cb[idx] (single f32 sub).
__global__ __launch_bounds__(256, 2)
void k_layer(float* __restrict__ R,
             const float* __restrict__ cbl,    // [K_][D_]
             const float* __restrict__ cbTl,   // [D_][K_]
             const float* __restrict__ y2fl,   // [K_]
             float* __restrict__ codes_out,    // [N_] (floats)
             float* __restrict__ loss_acc)
{
  __shared__ float As[BK][BM + 4];
  __shared__ float Bs[BK][BN + 4];
  __shared__ float x2s[BM];
  __shared__ float y2s[K_];
  __shared__ float wss[4];

  const int tid = threadIdx.x;
  const int tm = tid >> 4;   // 0..15 sample group
  const int tn = tid & 15;   // 0..15 code group
  const int n0 = blockIdx.x * BM;

  // stage this layer's y2 into LDS
#pragma unroll
  for (int c = 0; c < 4; ++c) y2s[tid + 256*c] = y2fl[tid + 256*c];

  // numpy-pairwise x2 per row of this block
  if (tid < BM) {
    const int n = n0 + tid;
    x2s[tid] = pairwise_sq_sum128(&R[(size_t)(n < N_ ? n : 0) * D_]);
  }
  // first __syncthreads() inside the kp loop covers x2s/y2s visibility

  float bv1[8]; int bj1[8];
#pragma unroll
  for (int i = 0; i < 8; ++i) { bv1[i] = 3.0e38f; bj1[i] = 0; }

  for (int ch = 0; ch < K_/BN; ++ch) {
    const int c0 = ch * BN;
    float acc[8][8];
#pragma unroll
    for (int i = 0; i < 8; ++i)
#pragma unroll
      for (int j = 0; j < 8; ++j) acc[i][j] = 0.f;

    for (int kp = 0; kp < D_/BK; ++kp) {
      const int k0 = kp * BK;
      __syncthreads();
      { // stage A (k-major)
        const int ri = tid >> 2;
        const int kq = (tid & 3) * 4;
#pragma unroll
        for (int h = 0; h < 2; ++h) {
          const int m = ri + h*64;
          float4 v = make_float4(0.f, 0.f, 0.f, 0.f);
          if (n0 + m < N_) v = *(const float4*)&R[(size_t)(n0 + m)*D_ + k0 + kq];
          As[kq+0][m] = v.x; As[kq+1][m] = v.y; As[kq+2][m] = v.z; As[kq+3][m] = v.w;
        }
      }
      { // stage B
        const int k  = tid >> 4;
        const int n8 = (tid & 15) * 8;
        const float* src = &cbTl[(size_t)(k0 + k)*K_ + c0 + n8];
        *(float4*)&Bs[k][n8]   = *(const float4*)src;
        *(float4*)&Bs[k][n8+4] = *(const float4*)(src + 4);
      }
      __syncthreads();
#pragma unroll
      for (int k = 0; k < BK; ++k) {   // strictly increasing k: exact BLAS chain
        const float4 a0 = *(const float4*)&As[k][tm*4];
        const float4 a1 = *(const float4*)&As[k][64 + tm*4];
        const float4 b0 = *(const float4*)&Bs[k][tn*4];
        const float4 b1 = *(const float4*)&Bs[k][64 + tn*4];
        const float av[8] = {a0.x,a0.y,a0.z,a0.w, a1.x,a1.y,a1.z,a1.w};
        const float bv[8] = {b0.x,b0.y,b0.z,b0.w, b1.x,b1.y,b1.z,b1.w};
#pragma unroll
        for (int i = 0; i < 8; ++i)
#pragma unroll
          for (int j = 0; j < 8; ++j)
            acc[i][j] = fmaf(av[i], bv[j], acc[i][j]);
      }
    }

    // chunk epilogue: dist = fl(fl(x2+y2) - fl(2*acc)); per-row argmin (top-1)
#pragma unroll
    for (int i = 0; i < 8; ++i) {
      const int m = (i < 4) ? (tm*4 + i) : (64 + tm*4 + (i - 4));
      const float x2i = x2s[m];
      float v1 = 3.0e38f; int j1 = 0;
#pragma unroll
      for (int j = 0; j < 8; ++j) {
        const int code = c0 + ((j < 4) ? (tn*4 + j) : (64 + tn*4 + (j - 4)));
        const float t1 = __fadd_rn(x2i, y2s[code]);
        const float dv = __fsub_rn(t1, __fmul_rn(2.0f, acc[i][j]));
        if (better(dv, code, v1, j1)) { v1 = dv; j1 = code; }
      }
#pragma unroll
      for (int off = 1; off < 16; off <<= 1) {  // 16 tn-lanes are contiguous in wave
        const float w1 = __shfl_xor(v1, off);
        const int  i1 = __shfl_xor(j1, off);
        if (better(w1, i1, v1, j1)) { v1 = w1; j1 = i1; }
      }
      if (better(v1, j1, bv1[i], bj1[i])) { bv1[i] = v1; bj1[i] = j1; }
    }
  }

  // residual update + codes + loss partial
  float ss = 0.f;
#pragma unroll
  for (int i = 0; i < 8; ++i) {
    const int m = (i < 4) ? (tm*4 + i) : (64 + tm*4 + (i - 4));
    const int n = n0 + m;
    if (n < N_) {
      float* xr = &R[(size_t)n*D_ + tn*8];
      const float4 x0 = *(const float4*)xr;
      const float4 x1 = *(const float4*)(xr + 4);
      const int j1 = bj1[i];   // uniform across the 16 tn lanes
      const float* c1 = &cbl[(size_t)j1*D_ + tn*8];
      const float4 q0 = *(const float4*)c1;
      const float4 q1 = *(const float4*)(c1 + 4);
      float4 r0, r1;
      r0.x = __fsub_rn(x0.x, q0.x); r0.y = __fsub_rn(x0.y, q0.y);
      r0.z = __fsub_rn(x0.z, q0.z); r0.w = __fsub_rn(x0.w, q0.w);
      r1.x = __fsub_rn(x1.x, q1.x); r1.y = __fsub_rn(x1.y, q1.y);
      r1.z = __fsub_rn(x1.z, q1.z); r1.w = __fsub_rn(x1.w, q1.w);
      *(float4*)xr = r0;
      *(float4*)(xr + 4) = r1;
      ss += r0.x*r0.x + r0.y*r0.y + r0.z*r0.z + r0.w*r0.w
          + r1.x*r1.x + r1.y*r1.y + r1.z*r1.z + r1.w*r1.w;
      if (tn == 0) codes_out[n] = (float)j1;
    }
  }
#pragma unroll
  for (int off = 1; off < 64; off <<= 1) ss += __shfl_xor(ss, off);
  if ((tid & 63) == 0) wss[tid >> 6] = ss;
  __syncthreads();
  if (tid == 0) atomicAdd(loss_acc, wss[0] + wss[1] + wss[2] + wss[3]);
}

// ---------------- finalize: quantized = z - R_final, transposed back ----------------
__global__ __launch_bounds__(256)
void k_finalize_quant(const float* __restrict__ z, const float* __restrict__ R,
                      float* __restrict__ out) {
  __shared__ float tile[32][33];
  const int t0 = blockIdx.x * 32;
  const int d0 = blockIdx.y * 32;
  const int b  = blockIdx.z;
  const int tid = threadIdx.x;
  {
    const int ii = tid & 31; const int jj0 = (tid >> 5) * 4;
#pragma unroll
    for (int r = 0; r < 4; ++r) {
      const int jj = jj0 + r;
      tile[ii][jj] = (t0 + jj < T_) ? R[((size_t)(b*T_ + t0 + jj))*D_ + d0 + ii] : 0.f;
    }
  }
  __syncthreads();
  {
    const int jj = tid & 31; const int ii0 = (tid >> 5) * 4;
#pragma unroll
    for (int r = 0; r < 4; ++r) {
      const int ii = ii0 + r;
      if (t0 + jj < T_) {
        const size_t gi = ((size_t)(b*D_ + d0 + ii))*T_ + t0 + jj;
        out[gi] = __fsub_rn(z[gi], tile[ii][jj]);
      }
    }
  }
}

__global__ void k_finalize_loss(const float* __restrict__ loss_acc, float* __restrict__ out2) {
  const float lv = (float)((double)loss_acc[0] / (double)((size_t)N_ * D_));
  out2[0] = lv;
  out2[1] = lv;
}

// ---------------- host launch ----------------
extern "C" void kernel_launch(void* const* d_in, const int* in_sizes, int n_in,
                              void* d_out, int out_size, void* d_ws, size_t ws_size,
                              hipStream_t stream) {
  const float* z  = (const float*)d_in[0];
  const float* cb = (const float*)d_in[1];
  float* out = (float*)d_out;

  char* ws = (char*)d_ws;
  const size_t OFF_R    = 0;
  const size_t OFF_CBT  = OFF_R + (size_t)N_ * D_ * 4;          // 36,864,000
  const size_t OFF_Y2F  = OFF_CBT + (size_t)L_ * K_ * D_ * 4;   // 41,058,304
  const size_t OFF_LOSS = OFF_Y2F + (size_t)L_ * K_ * 4;        // 41,091,072

  float* R     = (float*)(ws + OFF_R);
  float* cbT   = (float*)(ws + OFF_CBT);
  float* y2f   = (float*)(ws + OFF_Y2F);
  float* lossp = (float*)(ws + OFF_LOSS);

  hipMemsetAsync(lossp, 0, sizeof(float), stream);

  k_transpose_z<<<dim3((T_ + 31)/32, D_/32, B_), 256, 0, stream>>>(z, R);
  k_transpose_cb<<<dim3(K_/32, D_/32, L_), 256, 0, stream>>>(cb, cbT);
  k_y2<<<(L_ * K_)/256, 256, 0, stream>>>(cb, y2f);

  const int nblk = (N_ + BM - 1) / BM;  // 563
  for (int l = 0; l < L_; ++l) {
    k_layer<<<nblk, 256, 0, stream>>>(
        R,
        cb  + (size_t)l * K_ * D_,
        cbT + (size_t)l * D_ * K_,
        y2f + (size_t)l * K_,
        out + (size_t)N_ * D_ + (size_t)l * N_,
        lossp);
  }

  k_finalize_quant<<<dim3((T_ + 31)/32, D_/32, B_), 256, 0, stream>>>(z, R, out);
  k_finalize_loss<<<1, 1, 0, stream>>>(lossp, out + (size_t)N_ * D_ + (size_t)L_ * N_);
}